// Round 11
// baseline (140.568 us; speedup 1.0000x reference)
//
#include <hip/hip_runtime.h>
#include <math.h>

#define NT 1024
#define PW 66      // padded LDS row stride
#define RR 52      // LDS buffer rows (52 X rows / 50 r rows / 48 v rows + ring)

// Two launches: chunk<15,FIRST> then chunk<14,LAST>. 256 blocks (1 per CU),
// block = half image (32 core rows + 16-row internal halo; 48 v-rows).
//
// Sweep geometry (round 10): lane owns ONE column (c = tid&63) and THREE cell
// rows (L = 1+3*ty+j, ty = tid>>6, j=0..2), computing ALL 16 channels in-lane.
// Weight accesses w[o*9+t] are wave-uniform with compile-time indices -> the
// compiler s_loads them into SGPRs; v_fma takes the weight as the one allowed
// SGPR operand. This removes the per-lane weight arrays (the 64-VGPR arch cap
// forced them into AGPRs; every use was a v_accvgpr_read VALU op ~doubling
// VALU issue in r5-r9) AND removes all cross-lane channel-max shuffles
// (24 ds_swizzle/sweep -> 0; LDS ops 78 -> 18 per wave per sweep).
template<int NIT, bool FIRST, bool LAST>
__global__ __launch_bounds__(NT)
void vin_chunk(const float* __restrict__ layout,
               const float* __restrict__ heatmap,
               const float* __restrict__ h_w,
               const float* __restrict__ h_b,
               const float* __restrict__ r_w,
               const float* __restrict__ q_w,
               const float* __restrict__ w,
               const float* __restrict__ fc_w,
               const int* __restrict__ S1,
               const int* __restrict__ S2,
               float* __restrict__ vg,
               float* __restrict__ out)
{
    __shared__ float rh[28];
    __shared__ float r_s[RR * PW];   // X0, then r   (r_s row M <-> image row vlo-1+M)
    __shared__ float va[RR * PW];    // X1, then v ping (v row L <-> image row vlo+L-1)
    __shared__ float vb[RR * PW];    // X2, then v pong

    const int b2   = blockIdx.x;
    const int b    = b2 >> 1;
    const int half = b2 & 1;
    const int vlo  = half ? 16 : 0;
    const int tid  = threadIdx.x;

    // B0: zero everything (borders must be 0)
    for (int i = tid; i < RR * PW; i += NT) { r_s[i] = 0.f; va[i] = 0.f; vb[i] = 0.f; }
    __syncthreads();

    // collapse 150-ch h-conv + 1x1 r-conv into 28 coeffs (32 threads per coeff)
    if (tid < 896) {
        const int coeff = tid >> 5, j = tid & 31;
        float s = 0.f;
        for (int c = j; c < 150; c += 32)
            s += r_w[c] * ((coeff < 27) ? h_w[c * 27 + coeff] : h_b[c]);
        s += __shfl_xor(s, 1, 32);  s += __shfl_xor(s, 2, 32);
        s += __shfl_xor(s, 4, 32);  s += __shfl_xor(s, 8, 32);
        s += __shfl_xor(s, 16, 32);
        if (j == 0) rh[coeff] = s;
    }
    // stage X rows M=0..51 <-> image rows vlo-2..vlo+49 (zero OOB kept from memset)
    const float* X0 = layout  + (size_t)b * 2 * 4096;
    const float* X1 = X0 + 4096;
    const float* X2 = heatmap + (size_t)b * 4096;
    for (int i = tid; i < RR * 64; i += NT) {
        const int M = i >> 6, col = i & 63;
        const int ir = vlo - 2 + M;
        if (ir >= 0 && ir < 64) {
            const int s = ir * 64 + col, d = M * PW + col + 1;
            r_s[d] = X0[s]; va[d] = X1[s]; vb[d] = X2[s];
        }
    }
    __syncthreads();  // B1: X + rh ready

    // r (rows 0..49, cols 0..63) into registers; window top X-row == dest r-row
    float rv[4];
    int   rpx[4];
    #pragma unroll
    for (int k2 = 0; k2 < 4; ++k2) {
        const int i = tid + k2 * NT;
        rpx[k2] = -1;
        if (i < 50 * 64) {
            const int row = i >> 6, col = i & 63;
            float acc = rh[27];
            #pragma unroll
            for (int dy = 0; dy < 3; ++dy)
                #pragma unroll
                for (int dx = 0; dx < 3; ++dx) {
                    const int idx = (row + dy) * PW + col + dx;
                    acc = fmaf(rh[0 * 9 + dy * 3 + dx], r_s[idx], acc);
                    acc = fmaf(rh[1 * 9 + dy * 3 + dx], va[idx],  acc);
                    acc = fmaf(rh[2 * 9 + dy * 3 + dx], vb[idx],  acc);
                }
            const int ir = vlo - 1 + row;
            rv[k2]  = (ir >= 0 && ir < 64) ? acc : 0.f;  // true zero padding
            rpx[k2] = row * PW + col + 1;
        }
    }
    __syncthreads();  // B2: X consumed

    // overwrite: r -> r_s, re-zero v buffers
    for (int i = tid; i < RR * PW; i += NT) { va[i] = 0.f; vb[i] = 0.f; }
    #pragma unroll
    for (int k2 = 0; k2 < 4; ++k2) if (rpx[k2] >= 0) r_s[rpx[k2]] = rv[k2];
    __syncthreads();  // B3: r ready, v buffers zero

    // per-lane geometry: one column, three cell rows
    const int c  = tid & 63;        // image col (LDS col c+1)
    const int ty = tid >> 6;        // 0..15
    const int L0 = 1 + 3 * ty;      // first owned v row (LDS); window rows 3ty..3ty+4

    // stage v (non-FIRST) rows 1..48 <- vg image rows vlo..vlo+47
    if (!FIRST) {
        for (int i = tid; i < 48 * 64; i += NT) {
            const int L = (i >> 6) + 1, col = i & 63;
            va[L * PW + col + 1] = vg[b * 4096 + (vlo + L - 1) * 64 + col];
        }
    }

    // rq[j][o] = conv3x3(r, q_w[o]) at (row L0+j, col c); v0 = max_o rq if FIRST
    float rq[3][16];
    {
        float rn[5][3];
        #pragma unroll
        for (int i = 0; i < 5; ++i)
            #pragma unroll
            for (int d = 0; d < 3; ++d)
                rn[i][d] = r_s[(3 * ty + i) * PW + c + d];
        float m0[3];
        #pragma unroll
        for (int o = 0; o < 16; ++o) {
            #pragma unroll
            for (int j = 0; j < 3; ++j) {
                float q = 0.f;
                q = fmaf(q_w[o*9+0], rn[j+0][0], q); q = fmaf(q_w[o*9+1], rn[j+0][1], q); q = fmaf(q_w[o*9+2], rn[j+0][2], q);
                q = fmaf(q_w[o*9+3], rn[j+1][0], q); q = fmaf(q_w[o*9+4], rn[j+1][1], q); q = fmaf(q_w[o*9+5], rn[j+1][2], q);
                q = fmaf(q_w[o*9+6], rn[j+2][0], q); q = fmaf(q_w[o*9+7], rn[j+2][1], q); q = fmaf(q_w[o*9+8], rn[j+2][2], q);
                rq[j][o] = q;
                m0[j] = (o == 0) ? q : fmaxf(m0[j], q);
            }
        }
        if (FIRST) {
            #pragma unroll
            for (int j = 0; j < 3; ++j)
                va[(L0 + j) * PW + c + 1] = m0[j];
        }
    }
    __syncthreads();  // B4: v0 / staged v ready

    // NIT sweeps: all-16-channels-in-lane, weights via SGPR (uniform s_load)
    float* vcur = va;
    float* vnxt = vb;
    #pragma unroll 1
    for (int it = 0; it < NIT; ++it) {
        float vn[5][3];
        #pragma unroll
        for (int i = 0; i < 5; ++i)
            #pragma unroll
            for (int d = 0; d < 3; ++d)
                vn[i][d] = vcur[(3 * ty + i) * PW + c + d];
        float m[3];
        #pragma unroll
        for (int o = 0; o < 16; ++o) {
            #pragma unroll
            for (int j = 0; j < 3; ++j) {
                float q = rq[j][o];
                q = fmaf(w[o*9+0], vn[j+0][0], q); q = fmaf(w[o*9+1], vn[j+0][1], q); q = fmaf(w[o*9+2], vn[j+0][2], q);
                q = fmaf(w[o*9+3], vn[j+1][0], q); q = fmaf(w[o*9+4], vn[j+1][1], q); q = fmaf(w[o*9+5], vn[j+1][2], q);
                q = fmaf(w[o*9+6], vn[j+2][0], q); q = fmaf(w[o*9+7], vn[j+2][1], q); q = fmaf(w[o*9+8], vn[j+2][2], q);
                m[j] = (o == 0) ? q : fmaxf(m[j], q);
            }
        }
        #pragma unroll
        for (int j = 0; j < 3; ++j)
            vnxt[(L0 + j) * PW + c + 1] = m[j];
        __syncthreads();
        float* t = vcur; vcur = vnxt; vnxt = t;
    }

    // writeback core rows (image half*32 .. half*32+31; L = ir - vlo + 1)
    if (!LAST) {
        for (int i = tid; i < 32 * 64; i += NT) {
            const int ir = half * 32 + (i >> 6), col = i & 63;
            vg[b * 4096 + ir * 64 + col] = vcur[(ir - vlo + 1) * PW + col + 1];
        }
    } else {
        float* out_v = out + 1024 + (size_t)b * 4096;
        for (int i = tid; i < 32 * 64; i += NT) {
            const int ir = half * 32 + (i >> 6), col = i & 63;
            out_v[ir * 64 + col] = vcur[(ir - vlo + 1) * PW + col + 1];
        }
    }
    if (FIRST) {
        float* out_r = out + 1024 + (size_t)128 * 4096 + (size_t)b * 4096;
        float* out_h = out + 1024 + (size_t)256 * 4096 + (size_t)b * 4096;
        for (int i = tid; i < 32 * 64; i += NT) {
            const int ir = half * 32 + (i >> 6), col = i & 63;
            out_r[ir * 64 + col] = r_s[(ir - vlo + 1) * PW + col + 1];
            out_h[ir * 64 + col] = X2[ir * 64 + col];
        }
    }

    if (LAST) {
        const int s1 = S1[b], s2 = S2[b];
        if ((s1 >> 5) == half && tid == 0) {
            float q16[16];
            #pragma unroll
            for (int o = 0; o < 16; ++o) {
                float acc = 0.f;
                #pragma unroll
                for (int dy = 0; dy < 3; ++dy)
                    #pragma unroll
                    for (int dx = 0; dx < 3; ++dx) {
                        const int li = (s1 + dy - vlo) * PW + s2 + dx;
                        acc = fmaf(q_w[o * 9 + dy * 3 + dx], r_s[li], acc);
                        acc = fmaf(w[o * 9 + dy * 3 + dx],  vcur[li], acc);
                    }
                q16[o] = acc;
            }
            float lg[4];
            #pragma unroll
            for (int j = 0; j < 4; ++j) {
                float a = 0.f;
                #pragma unroll
                for (int o = 0; o < 16; ++o) a = fmaf(fc_w[j * 16 + o], q16[o], a);
                lg[j] = a;
            }
            const float m  = fmaxf(fmaxf(lg[0], lg[1]), fmaxf(lg[2], lg[3]));
            const float e0 = expf(lg[0] - m), e1 = expf(lg[1] - m);
            const float e2 = expf(lg[2] - m), e3 = expf(lg[3] - m);
            const float s  = e0 + e1 + e2 + e3;
            out[b * 4 + 0] = lg[0]; out[b * 4 + 1] = lg[1];
            out[b * 4 + 2] = lg[2]; out[b * 4 + 3] = lg[3];
            out[512 + b * 4 + 0] = e0 / s; out[512 + b * 4 + 1] = e1 / s;
            out[512 + b * 4 + 2] = e2 / s; out[512 + b * 4 + 3] = e3 / s;
        }
    }
}

extern "C" void kernel_launch(void* const* d_in, const int* in_sizes, int n_in,
                              void* d_out, int out_size, void* d_ws, size_t ws_size,
                              hipStream_t stream) {
    const float* layout  = (const float*)d_in[0];
    const float* heatmap = (const float*)d_in[1];
    const float* h_w     = (const float*)d_in[2];
    const float* h_b     = (const float*)d_in[3];
    const float* r_w     = (const float*)d_in[4];
    const float* q_w     = (const float*)d_in[5];
    const float* w       = (const float*)d_in[6];
    const float* fc_w    = (const float*)d_in[7];
    const int*   S1      = (const int*)d_in[8];
    const int*   S2      = (const int*)d_in[9];
    float* out = (float*)d_out;
    float* vg  = (float*)d_ws;   // 128*4096 f32 = 2 MB

    hipLaunchKernelGGL((vin_chunk<15, true,  false>), dim3(256), dim3(NT), 0, stream,
                       layout, heatmap, h_w, h_b, r_w, q_w, w, fc_w, S1, S2, vg, out);
    hipLaunchKernelGGL((vin_chunk<14, false, true>),  dim3(256), dim3(NT), 0, stream,
                       layout, heatmap, h_w, h_b, r_w, q_w, w, fc_w, S1, S2, vg, out);
}

// Round 12
// 134.104 us; speedup vs baseline: 1.0482x; 1.0482x over previous
//
#include <hip/hip_runtime.h>
#include <math.h>

#define NT 1024
#define PW 66             // padded row stride (cols -1..64)
#define SZ (50 * PW)      // one steady buffer: rows 0..49
#define XR 52             // X staging rows

// Pin to AGPR (unified file) — proven pattern from round 6.
#define AW(arr, idx, val) asm("v_accvgpr_write_b32 %0, %1" : "=a"(arr[idx]) : "v"(val))
#define AR(dst, arr, idx) asm("v_accvgpr_read_b32 %0, %1" : "=v"(dst) : "a"(arr[idx]))

// Two launches: chunk<15,FIRST> then chunk<14,LAST>. 256 blocks, block = half image
// (32 core rows + 16-row internal halo; v rows 1..48 in LDS index space where
// LDS row L <-> image row vlo+L-1 for BOTH r and v).
//
// Wave w: g2 = w&1 -> channels 8*g2..8*g2+7 (WAVE-UNIFORM -> 72 weights live in
// SGPRs via readfirstlane, loaded once); band = w>>1 -> 6 v-rows; lane = column.
// All 8 channels in-lane (max = 7 v_max, no shuffles). Cross-half (16-ch) max via
// two v slabs: wave writes its 8-ch partial to slab A (g2=0) or B (g2=1);
// readers combine fmaxf(A,B) in the window load. B-slabs armed to -inf,
// A-slabs to 0 => borders combine to exactly 0 forever. rq[48] pinned in AGPRs.
template<int NIT, bool FIRST, bool LAST>
__global__ __launch_bounds__(NT)
void vin_chunk(const float* __restrict__ layout,
               const float* __restrict__ heatmap,
               const float* __restrict__ h_w,
               const float* __restrict__ h_b,
               const float* __restrict__ r_w,
               const float* __restrict__ q_w,
               const float* __restrict__ w,
               const float* __restrict__ fc_w,
               const int* __restrict__ S1,
               const int* __restrict__ S2,
               float* __restrict__ vg,
               float* __restrict__ out)
{
    __shared__ float S[5 * SZ];   // 66 KB
    __shared__ float rh[28];
    float* r_s = S;               // steady: r rows 0..49
    float* A0  = S + SZ;          // v slab A (ping)
    float* B0  = S + 2 * SZ;      // v slab B (ping)
    float* A1  = S + 3 * SZ;      // v slab A (pong)
    float* B1  = S + 4 * SZ;      // v slab B (pong)
    float* X0  = S;               // staging aliases: 52*66 = 3432 floats each
    float* X1  = S + 3432;
    float* X2  = S + 6864;        // ends at 10296 < 5*SZ

    const int b2   = blockIdx.x;
    const int b    = b2 >> 1;
    const int half = b2 & 1;
    const int vlo  = half ? 16 : 0;
    const int tid  = threadIdx.x;

    // zero X staging region (OOB rows must read 0 during r-conv)
    for (int i = tid; i < 3 * 3432; i += NT) S[i] = 0.f;
    __syncthreads();

    // collapse 150-ch h-conv + 1x1 r-conv into 28 coeffs
    if (tid < 896) {
        const int coeff = tid >> 5, j = tid & 31;
        float s = 0.f;
        for (int cch = j; cch < 150; cch += 32)
            s += r_w[cch] * ((coeff < 27) ? h_w[cch * 27 + coeff] : h_b[cch]);
        s += __shfl_xor(s, 1, 32);  s += __shfl_xor(s, 2, 32);
        s += __shfl_xor(s, 4, 32);  s += __shfl_xor(s, 8, 32);
        s += __shfl_xor(s, 16, 32);
        if (j == 0) rh[coeff] = s;
    }
    // stage X rows M=0..51 <-> image rows vlo-2..vlo+49
    const float* X0g = layout  + (size_t)b * 2 * 4096;
    const float* X1g = X0g + 4096;
    const float* X2g = heatmap + (size_t)b * 4096;
    for (int i = tid; i < XR * 64; i += NT) {
        const int M = i >> 6, col = i & 63;
        const int ir = vlo - 2 + M;
        if (ir >= 0 && ir < 64) {
            const int s = ir * 64 + col, d = M * PW + col + 1;
            X0[d] = X0g[s]; X1[d] = X1g[s]; X2[d] = X2g[s];
        }
    }
    __syncthreads();  // X + rh ready

    // r rows 0..49 into registers (r row M needs X rows M..M+2)
    float rv[4];
    int   rpx[4];
    #pragma unroll
    for (int k2 = 0; k2 < 4; ++k2) {
        const int i = tid + k2 * NT;
        rpx[k2] = -1;
        if (i < 50 * 64) {
            const int row = i >> 6, col = i & 63;
            float acc = rh[27];
            #pragma unroll
            for (int dy = 0; dy < 3; ++dy)
                #pragma unroll
                for (int dx = 0; dx < 3; ++dx) {
                    const int idx = (row + dy) * PW + col + dx;
                    acc = fmaf(rh[0 * 9 + dy * 3 + dx], X0[idx], acc);
                    acc = fmaf(rh[1 * 9 + dy * 3 + dx], X1[idx], acc);
                    acc = fmaf(rh[2 * 9 + dy * 3 + dx], X2[idx], acc);
                }
            const int ir = vlo - 1 + row;
            rv[k2]  = (ir >= 0 && ir < 64) ? acc : 0.f;  // true zero padding
            rpx[k2] = row * PW + col + 1;
        }
    }
    __syncthreads();  // X consumed

    // write r over X0; arm slabs (A=0, B=-inf); stage v into A0 interior if !FIRST
    for (int i = tid; i < SZ; i += NT) {
        const int row = i / PW, cc = i - row * PW;
        const bool interior = (row >= 1) & (row <= 48) & (cc >= 1) & (cc <= 64);
        float a0v = 0.f;
        if (!FIRST && interior)
            a0v = vg[b * 4096 + (vlo + row - 1) * 64 + (cc - 1)];
        A0[i] = a0v;
        B0[i] = -INFINITY;
        A1[i] = 0.f;
        B1[i] = -INFINITY;
    }
    #pragma unroll
    for (int k2 = 0; k2 < 4; ++k2) if (rpx[k2] >= 0) r_s[rpx[k2]] = rv[k2];
    __syncthreads();  // r + armed slabs ready

    // per-lane geometry
    const int wid  = tid >> 6, lane = tid & 63;
    const int g2   = wid & 1;        // channel half: channels 8*g2..8*g2+7
    const int band = wid >> 1;       // 0..7
    const int rb0  = band * 6;       // window-top row for j=0; v rows rb0+1..rb0+6
    const int c    = lane;           // column; window padded cols c..c+2
    const int g2u  = __builtin_amdgcn_readfirstlane(g2);

    // rq[o*6+j] -> AGPRs; v0 partials if FIRST (each wave -> its slab)
    float rqa[48];
    {
        float wq[72];
        #pragma unroll
        for (int t = 0; t < 72; ++t)
            wq[t] = __int_as_float(__builtin_amdgcn_readfirstlane(
                        __float_as_int(q_w[g2u * 72 + t])));
        float* vdst = g2 ? B0 : A0;
        float a0[3], a1[3], a2[3];
        #pragma unroll
        for (int d = 0; d < 3; ++d) {
            a0[d] = r_s[rb0 * PW + c + d];
            a1[d] = r_s[(rb0 + 1) * PW + c + d];
        }
        #pragma unroll
        for (int j = 0; j < 6; ++j) {
            #pragma unroll
            for (int d = 0; d < 3; ++d) a2[d] = r_s[(rb0 + j + 2) * PW + c + d];
            float m;
            #pragma unroll
            for (int o = 0; o < 8; ++o) {
                float q = 0.f;
                q = fmaf(wq[o*9+0], a0[0], q); q = fmaf(wq[o*9+1], a0[1], q); q = fmaf(wq[o*9+2], a0[2], q);
                q = fmaf(wq[o*9+3], a1[0], q); q = fmaf(wq[o*9+4], a1[1], q); q = fmaf(wq[o*9+5], a1[2], q);
                q = fmaf(wq[o*9+6], a2[0], q); q = fmaf(wq[o*9+7], a2[1], q); q = fmaf(wq[o*9+8], a2[2], q);
                AW(rqa, o * 6 + j, q);
                m = (o == 0) ? q : fmaxf(m, q);
            }
            if (FIRST) vdst[(rb0 + 1 + j) * PW + c + 1] = m;
            #pragma unroll
            for (int d = 0; d < 3; ++d) { a0[d] = a1[d]; a1[d] = a2[d]; }
        }
    }

    // sweep weights: wave-uniform -> SGPRs, loaded ONCE
    float ws[72];
    #pragma unroll
    for (int t = 0; t < 72; ++t)
        ws[t] = __int_as_float(__builtin_amdgcn_readfirstlane(
                    __float_as_int(w[g2u * 72 + t])));
    __syncthreads();  // v0 / staged v ready

    // NIT sweeps; window combines the two slabs at read time
    float* cA = A0; float* cB = B0;
    float* nA = A1; float* nB = B1;
    #pragma unroll 1
    for (int it = 0; it < NIT; ++it) {
        float* ndst = g2 ? nB : nA;
        float a0[3], a1[3], a2[3];
        #pragma unroll
        for (int d = 0; d < 3; ++d) {
            a0[d] = fmaxf(cA[rb0 * PW + c + d],       cB[rb0 * PW + c + d]);
            a1[d] = fmaxf(cA[(rb0 + 1) * PW + c + d], cB[(rb0 + 1) * PW + c + d]);
        }
        #pragma unroll
        for (int j = 0; j < 6; ++j) {
            #pragma unroll
            for (int d = 0; d < 3; ++d)
                a2[d] = fmaxf(cA[(rb0 + j + 2) * PW + c + d],
                              cB[(rb0 + j + 2) * PW + c + d]);
            float m;
            #pragma unroll
            for (int o = 0; o < 8; ++o) {
                float q;
                AR(q, rqa, o * 6 + j);
                q = fmaf(ws[o*9+0], a0[0], q); q = fmaf(ws[o*9+1], a0[1], q); q = fmaf(ws[o*9+2], a0[2], q);
                q = fmaf(ws[o*9+3], a1[0], q); q = fmaf(ws[o*9+4], a1[1], q); q = fmaf(ws[o*9+5], a1[2], q);
                q = fmaf(ws[o*9+6], a2[0], q); q = fmaf(ws[o*9+7], a2[1], q); q = fmaf(ws[o*9+8], a2[2], q);
                m = (o == 0) ? q : fmaxf(m, q);
            }
            ndst[(rb0 + 1 + j) * PW + c + 1] = m;
            #pragma unroll
            for (int d = 0; d < 3; ++d) { a0[d] = a1[d]; a1[d] = a2[d]; }
        }
        __syncthreads();
        float* t;
        t = cA; cA = nA; nA = t;
        t = cB; cB = nB; nB = t;
    }

    // writeback core rows (image half*32 .. half*32+31; L = ir - vlo + 1)
    if (!LAST) {
        for (int i = tid; i < 32 * 64; i += NT) {
            const int ir = half * 32 + (i >> 6), col = i & 63;
            const int li = (ir - vlo + 1) * PW + col + 1;
            vg[b * 4096 + ir * 64 + col] = fmaxf(cA[li], cB[li]);
        }
    } else {
        float* out_v = out + 1024 + (size_t)b * 4096;
        for (int i = tid; i < 32 * 64; i += NT) {
            const int ir = half * 32 + (i >> 6), col = i & 63;
            const int li = (ir - vlo + 1) * PW + col + 1;
            out_v[ir * 64 + col] = fmaxf(cA[li], cB[li]);
        }
    }
    if (FIRST) {
        float* out_r = out + 1024 + (size_t)128 * 4096 + (size_t)b * 4096;
        float* out_h = out + 1024 + (size_t)256 * 4096 + (size_t)b * 4096;
        for (int i = tid; i < 32 * 64; i += NT) {
            const int ir = half * 32 + (i >> 6), col = i & 63;
            out_r[ir * 64 + col] = r_s[(ir - vlo + 1) * PW + col + 1];
            out_h[ir * 64 + col] = X2g[ir * 64 + col];
        }
    }

    if (LAST) {
        const int s1 = S1[b], s2 = S2[b];
        if ((s1 >> 5) == half && tid == 0) {
            float q16[16];
            #pragma unroll
            for (int o = 0; o < 16; ++o) {
                float acc = 0.f;
                #pragma unroll
                for (int dy = 0; dy < 3; ++dy)
                    #pragma unroll
                    for (int dx = 0; dx < 3; ++dx) {
                        const int li = (s1 + dy - vlo) * PW + s2 + dx;
                        acc = fmaf(q_w[o * 9 + dy * 3 + dx], r_s[li], acc);
                        acc = fmaf(w[o * 9 + dy * 3 + dx], fmaxf(cA[li], cB[li]), acc);
                    }
                q16[o] = acc;
            }
            float lg[4];
            #pragma unroll
            for (int j = 0; j < 4; ++j) {
                float a = 0.f;
                #pragma unroll
                for (int o = 0; o < 16; ++o) a = fmaf(fc_w[j * 16 + o], q16[o], a);
                lg[j] = a;
            }
            const float m  = fmaxf(fmaxf(lg[0], lg[1]), fmaxf(lg[2], lg[3]));
            const float e0 = expf(lg[0] - m), e1 = expf(lg[1] - m);
            const float e2 = expf(lg[2] - m), e3 = expf(lg[3] - m);
            const float s  = e0 + e1 + e2 + e3;
            out[b * 4 + 0] = lg[0]; out[b * 4 + 1] = lg[1];
            out[b * 4 + 2] = lg[2]; out[b * 4 + 3] = lg[3];
            out[512 + b * 4 + 0] = e0 / s; out[512 + b * 4 + 1] = e1 / s;
            out[512 + b * 4 + 2] = e2 / s; out[512 + b * 4 + 3] = e3 / s;
        }
    }
}

extern "C" void kernel_launch(void* const* d_in, const int* in_sizes, int n_in,
                              void* d_out, int out_size, void* d_ws, size_t ws_size,
                              hipStream_t stream) {
    const float* layout  = (const float*)d_in[0];
    const float* heatmap = (const float*)d_in[1];
    const float* h_w     = (const float*)d_in[2];
    const float* h_b     = (const float*)d_in[3];
    const float* r_w     = (const float*)d_in[4];
    const float* q_w     = (const float*)d_in[5];
    const float* w       = (const float*)d_in[6];
    const float* fc_w    = (const float*)d_in[7];
    const int*   S1      = (const int*)d_in[8];
    const int*   S2      = (const int*)d_in[9];
    float* out = (float*)d_out;
    float* vg  = (float*)d_ws;   // 128*4096 f32 = 2 MB

    hipLaunchKernelGGL((vin_chunk<15, true,  false>), dim3(256), dim3(NT), 0, stream,
                       layout, heatmap, h_w, h_b, r_w, q_w, w, fc_w, S1, S2, vg, out);
    hipLaunchKernelGGL((vin_chunk<14, false, true>),  dim3(256), dim3(NT), 0, stream,
                       layout, heatmap, h_w, h_b, r_w, q_w, w, fc_w, S1, S2, vg, out);
}